// Round 14
// baseline (52.589 us; speedup 1.0000x reference)
//
#include <hip/hip_runtime.h>
#include <math.h>

#define DDIM 2048
#define KP 8
#define BLOCK 256

typedef float f4 __attribute__((ext_vector_type(4)));

#if __has_builtin(__builtin_amdgcn_fdot2_f32_bf16)
#define HAVE_DOT2 1
typedef __bf16 bf2 __attribute__((ext_vector_type(2)));
#else
#define HAVE_DOT2 0
#endif

#if __has_builtin(__builtin_amdgcn_update_dpp)
#define HAVE_DPP 1
#else
#define HAVE_DPP 0
#endif

__device__ __forceinline__ unsigned short f32_to_bf16_rne(float f) {
    unsigned u = __float_as_uint(f);
    unsigned r = u + 0x7FFFu + ((u >> 16) & 1u);
    return (unsigned short)(r >> 16);
}

// Vector-form gelu: elementwise parts stay as f4 expressions so clang can
// emit v_pk_fma_f32 / v_pk_mul_f32 (2xf32 per instr); exp/rcp stay scalar
// (no packed trans ops exist).
__device__ __forceinline__ f4 gelu_f4(f4 x) {
    f4 x2 = x * x;
    f4 inner = x * (x2 * 0.044715f + 1.0f);
    f4 t = inner * -1.5957691216057308f;          // -2y
    f4 e;
    e.x = __expf(t.x); e.y = __expf(t.y);
    e.z = __expf(t.z); e.w = __expf(t.w);
    f4 den = e + 1.0f;
    f4 r;
    r.x = __builtin_amdgcn_rcpf(den.x); r.y = __builtin_amdgcn_rcpf(den.y);
    r.z = __builtin_amdgcn_rcpf(den.z); r.w = __builtin_amdgcn_rcpf(den.w);
    return x * r;                                  // x * sigmoid(2y)
}

__device__ __forceinline__ float wave_reduce_add(float v) {
#pragma unroll
    for (int m = 32; m >= 1; m >>= 1) v += __shfl_xor(v, m, 64);
    return v;
}

#if HAVE_DPP
template <int CTRL>
__device__ __forceinline__ float dpp_add(float v) {
    int t = __builtin_amdgcn_update_dpp(0, __builtin_bit_cast(int, v),
                                        CTRL, 0xf, 0xf, true);
    return v + __builtin_bit_cast(float, t);
}
// Wave-64 sum entirely on the VALU pipe (no DS ops). Valid in LANE 63 ONLY.
__device__ __forceinline__ float wave_sum_dpp_lane63(float v) {
    v = dpp_add<0x111>(v);   // row_shr:1
    v = dpp_add<0x112>(v);   // row_shr:2
    v = dpp_add<0x114>(v);   // row_shr:4
    v = dpp_add<0x118>(v);   // row_shr:8  -> lane 15 of each row16 = row sum
    v = dpp_add<0x142>(v);   // row_bcast:15 -> lane63 = row3+row2
    v = dpp_add<0x143>(v);   // row_bcast:31 -> lane63 += (row0+row1)
    return v;
}
#endif

// Prologue: pb = bf16(protos) (32 KB, L1-resident for the main kernel);
// inv_pn[k] = 1/max(||bf16(proto_k)||, eps)  (norm of the ROUNDED values).
__global__ void proto_prep_kernel(const float* __restrict__ protos,
                                  unsigned short* __restrict__ pb,
                                  float* __restrict__ inv_pn) {
    const int k = blockIdx.x;
    const int tid = threadIdx.x;
    const float* p = protos + k * DDIM;
    float ss = 0.0f;
#pragma unroll
    for (int i = 0; i < 2; ++i) {
        int idx = tid + i * 256;                       // f4 index within row
        f4 a = reinterpret_cast<const f4*>(p)[idx];
        ushort4 u;
        u.x = f32_to_bf16_rne(a.x); u.y = f32_to_bf16_rne(a.y);
        u.z = f32_to_bf16_rne(a.z); u.w = f32_to_bf16_rne(a.w);
        float q;
        q = __uint_as_float((unsigned)u.x << 16); ss += q * q;
        q = __uint_as_float((unsigned)u.y << 16); ss += q * q;
        q = __uint_as_float((unsigned)u.z << 16); ss += q * q;
        q = __uint_as_float((unsigned)u.w << 16); ss += q * q;
        *reinterpret_cast<ushort4*>(&pb[(size_t)k * DDIM + idx * 4]) = u;
    }
    ss = wave_reduce_add(ss);
    __shared__ float red[4];
    const int wave = tid >> 6, lane = tid & 63;
    if (lane == 0) red[wave] = ss;
    __syncthreads();
    if (tid == 0)
        inv_pn[k] = 1.0f / fmaxf(sqrtf(red[0] + red[1] + red[2] + red[3]), 1e-12f);
}

// R13: R12 skeleton (2-row pair, cross-iter prefetch, DPP reduce, dot2,
// 1 barrier/pair) + packed-f32 vector math + tail-prefetch guard (the last
// iteration's clamped prefetch was 64 MB of wasted cache reads).
__global__ __launch_bounds__(BLOCK)
void fused_row_kernel(const float* __restrict__ x,
                      const unsigned short* __restrict__ pb,
                      const float* __restrict__ lt,
                      const float* __restrict__ lg,
                      const float* __restrict__ lb,
                      const float* __restrict__ inv_pn,
                      float* __restrict__ out, int nrows) {
    alignas(16) __shared__ float red[2][18][4];   // [buf][value][wave]

    const int tid = threadIdx.x;
    const int lane = tid & 63;
    const int wave = tid >> 6;

    const float tau = __expf(lt[0]);
    const float gamma = __expf(lg[0]);
    const float alpha = 1.0f / (1.0f + __expf(-lb[0]));
    const float inv_tau = 1.0f / tau;
    const float logK_div_tau = logf(8.0f) * inv_tau;

    float ipn[KP];
#pragma unroll
    for (int k = 0; k < KP; ++k) ipn[k] = inv_pn[k];

    const uint2* pb2 = reinterpret_cast<const uint2*>(pb);  // 4 bf16 per uint2
    const int G = gridDim.x;

    int buf = 0;
    int r0 = blockIdx.x;
    if (r0 >= nrows) return;

    // preload pair 0 (row r1 clamped branch-free if absent)
    f4 a0, b0, a1, b1;
    {
        const int r1c = (r0 + G < nrows) ? r0 + G : r0;
        const f4* x0 = reinterpret_cast<const f4*>(x + (size_t)r0 * DDIM);
        const f4* x1 = reinterpret_cast<const f4*>(x + (size_t)r1c * DDIM);
        a0 = x0[tid]; b0 = x0[tid + 256];
        a1 = x1[tid]; b1 = x1[tid + 256];
    }

    for (; r0 < nrows; r0 += 2 * G) {
        const int r1 = r0 + G;
        const bool has1 = r1 < nrows;

        f4 g0a = gelu_f4(a0);
        f4 g0b = gelu_f4(b0);
        f4 g1a = gelu_f4(a1);
        f4 g1b = gelu_f4(b1);

        // prefetch next pair now that a*/b* are dead. Uniform branch: skipped
        // only when the loop is about to exit (stale regs never consumed).
        {
            const int n0 = r0 + 2 * G;
            if (n0 < nrows) {
                const int n1 = n0 + G;
                const int n1c = (n1 < nrows) ? n1 : n0;
                const f4* xn0 = reinterpret_cast<const f4*>(x + (size_t)n0 * DDIM);
                const f4* xn1 = reinterpret_cast<const f4*>(x + (size_t)n1c * DDIM);
                a0 = xn0[tid]; b0 = xn0[tid + 256];
                a1 = xn1[tid]; b1 = xn1[tid + 256];
            }
        }

        float vals[18];
        {
            f4 s0 = g0a * g0a + g0b * g0b;    // pk_fma-able
            f4 s1 = g1a * g1a + g1b * g1b;
            vals[8] = (s0.x + s0.y) + (s0.z + s0.w);
            vals[17] = (s1.x + s1.y) + (s1.z + s1.w);
        }

#if HAVE_DOT2
        bf2 p0a, p0b, p0c, p0d, p1a, p1b, p1c, p1d;
        p0a.x = (__bf16)g0a.x; p0a.y = (__bf16)g0a.y;
        p0b.x = (__bf16)g0a.z; p0b.y = (__bf16)g0a.w;
        p0c.x = (__bf16)g0b.x; p0c.y = (__bf16)g0b.y;
        p0d.x = (__bf16)g0b.z; p0d.y = (__bf16)g0b.w;
        p1a.x = (__bf16)g1a.x; p1a.y = (__bf16)g1a.y;
        p1b.x = (__bf16)g1a.z; p1b.y = (__bf16)g1a.w;
        p1c.x = (__bf16)g1b.x; p1c.y = (__bf16)g1b.y;
        p1d.x = (__bf16)g1b.z; p1d.y = (__bf16)g1b.w;
#pragma unroll
        for (int k = 0; k < KP; ++k) {
            uint2 q0 = pb2[k * 512 + tid];
            uint2 q1 = pb2[k * 512 + 256 + tid];
            float t0, t1;
            t0 = __builtin_amdgcn_fdot2_f32_bf16(p0a, __builtin_bit_cast(bf2, q0.x), 0.0f, false);
            t1 = __builtin_amdgcn_fdot2_f32_bf16(p1a, __builtin_bit_cast(bf2, q0.x), 0.0f, false);
            t0 = __builtin_amdgcn_fdot2_f32_bf16(p0b, __builtin_bit_cast(bf2, q0.y), t0, false);
            t1 = __builtin_amdgcn_fdot2_f32_bf16(p1b, __builtin_bit_cast(bf2, q0.y), t1, false);
            t0 = __builtin_amdgcn_fdot2_f32_bf16(p0c, __builtin_bit_cast(bf2, q1.x), t0, false);
            t1 = __builtin_amdgcn_fdot2_f32_bf16(p1c, __builtin_bit_cast(bf2, q1.x), t1, false);
            t0 = __builtin_amdgcn_fdot2_f32_bf16(p0d, __builtin_bit_cast(bf2, q1.y), t0, false);
            t1 = __builtin_amdgcn_fdot2_f32_bf16(p1d, __builtin_bit_cast(bf2, q1.y), t1, false);
            vals[k] = t0;
            vals[9 + k] = t1;
        }
#else
#pragma unroll
        for (int k = 0; k < KP; ++k) {
            uint2 q0 = pb2[k * 512 + tid];
            uint2 q1 = pb2[k * 512 + 256 + tid];
            float c0 = __uint_as_float(q0.x << 16);
            float c1 = __uint_as_float(q0.x & 0xFFFF0000u);
            float c2 = __uint_as_float(q0.y << 16);
            float c3 = __uint_as_float(q0.y & 0xFFFF0000u);
            float c4 = __uint_as_float(q1.x << 16);
            float c5 = __uint_as_float(q1.x & 0xFFFF0000u);
            float c6 = __uint_as_float(q1.y << 16);
            float c7 = __uint_as_float(q1.y & 0xFFFF0000u);
            float t0, t1;
            t0 = fmaf(c0, g0a.x, c1 * g0a.y);
            t1 = fmaf(c0, g1a.x, c1 * g1a.y);
            t0 = fmaf(c2, g0a.z, t0); t0 = fmaf(c3, g0a.w, t0);
            t1 = fmaf(c2, g1a.z, t1); t1 = fmaf(c3, g1a.w, t1);
            t0 = fmaf(c4, g0b.x, t0); t0 = fmaf(c5, g0b.y, t0);
            t1 = fmaf(c4, g1b.x, t1); t1 = fmaf(c5, g1b.y, t1);
            t0 = fmaf(c6, g0b.z, t0); t0 = fmaf(c7, g0b.w, t0);
            t1 = fmaf(c6, g1b.z, t1); t1 = fmaf(c7, g1b.w, t1);
            vals[k] = t0;
            vals[9 + k] = t1;
        }
#endif

#if HAVE_DPP
#pragma unroll
        for (int v = 0; v < 18; ++v) vals[v] = wave_sum_dpp_lane63(vals[v]);
        if (lane == 63) {
#pragma unroll
            for (int v = 0; v < 18; ++v) red[buf][v][wave] = vals[v];
        }
#else
#pragma unroll
        for (int v = 0; v < 18; ++v) vals[v] = wave_reduce_add(vals[v]);
        if (lane == 0) {
#pragma unroll
            for (int v = 0; v < 18; ++v) red[buf][v][wave] = vals[v];
        }
#endif
        __syncthreads();   // ONE barrier per row pair (red double-buffered)

        float s[18];
#pragma unroll
        for (int v = 0; v < 18; ++v) {
            f4 r = *reinterpret_cast<const f4*>(red[buf][v]);  // broadcast b128
            s[v] = (r.x + r.y) + (r.z + r.w);
        }
        buf ^= 1;

        // gates, redundantly in every thread; no max-subtract (|z| <= tau)
        float gate0, gate1;
        {
            const float cn = __builtin_amdgcn_rcpf(fmaxf(sqrtf(s[8]), 1e-12f)) * tau;
            float e = 0.0f;
#pragma unroll
            for (int k = 0; k < KP; ++k)
                e += __expf(s[k] * ipn[k] * cn);
            float sms = __logf(e) * inv_tau - logK_div_tau;
            gate0 = 1.0f - alpha + alpha * __expf(-gamma * sms);
        }
        {
            const float cn = __builtin_amdgcn_rcpf(fmaxf(sqrtf(s[17]), 1e-12f)) * tau;
            float e = 0.0f;
#pragma unroll
            for (int k = 0; k < KP; ++k)
                e += __expf(s[9 + k] * ipn[k] * cn);
            float sms = __logf(e) * inv_tau - logK_div_tau;
            gate1 = 1.0f - alpha + alpha * __expf(-gamma * sms);
        }

        f4* o0 = reinterpret_cast<f4*>(out + (size_t)r0 * DDIM);
        f4 w0 = g0a * gate0;     // v_pk_mul_f32
        f4 w1 = g0b * gate0;
        __builtin_nontemporal_store(w0, &o0[tid]);
        __builtin_nontemporal_store(w1, &o0[tid + 256]);
        if (has1) {
            f4* o1 = reinterpret_cast<f4*>(out + (size_t)r1 * DDIM);
            f4 w2 = g1a * gate1;
            f4 w3 = g1b * gate1;
            __builtin_nontemporal_store(w2, &o1[tid]);
            __builtin_nontemporal_store(w3, &o1[tid + 256]);
        }
    }
}

extern "C" void kernel_launch(void* const* d_in, const int* in_sizes, int n_in,
                              void* d_out, int out_size, void* d_ws, size_t ws_size,
                              hipStream_t stream) {
    const float* x = (const float*)d_in[0];
    const float* protos = (const float*)d_in[1];
    const float* lt = (const float*)d_in[2];
    const float* lg = (const float*)d_in[3];
    const float* lb = (const float*)d_in[4];
    float* out = (float*)d_out;

    float* inv_pn = (float*)d_ws;                                // 8 floats
    unsigned short* pb = (unsigned short*)((char*)d_ws + 256);   // 32 KB bf16 protos

    const int nrows = in_sizes[0] / DDIM;

    proto_prep_kernel<<<KP, 256, 0, stream>>>(protos, pb, inv_pn);

    // 2048 blocks: 4 pair-iterations each (16384 rows); prefetch covers HBM lat
    int blocks = 2048;
    if (blocks > (nrows + 1) / 2) blocks = (nrows + 1) / 2;
    fused_row_kernel<<<blocks, BLOCK, 0, stream>>>(x, pb, lt, lg, lb, inv_pn,
                                                   out, nrows);
}

// Round 15
// 51.284 us; speedup vs baseline: 1.0254x; 1.0254x over previous
//
#include <hip/hip_runtime.h>
#include <math.h>

#define DDIM 2048
#define KP 8
#define BLOCK 256

typedef float f4 __attribute__((ext_vector_type(4)));

#if __has_builtin(__builtin_amdgcn_fdot2_f32_bf16)
#define HAVE_DOT2 1
typedef __bf16 bf2 __attribute__((ext_vector_type(2)));
#else
#define HAVE_DOT2 0
#endif

#if __has_builtin(__builtin_amdgcn_update_dpp)
#define HAVE_DPP 1
#else
#define HAVE_DPP 0
#endif

__device__ __forceinline__ unsigned short f32_to_bf16_rne(float f) {
    unsigned u = __float_as_uint(f);
    unsigned r = u + 0x7FFFu + ((u >> 16) & 1u);
    return (unsigned short)(r >> 16);
}

// Vector-form gelu: elementwise parts as f4 expressions (clang emits
// v_pk_fma_f32/v_pk_mul_f32); exp/rcp scalar (no packed trans ops).
__device__ __forceinline__ f4 gelu_f4(f4 x) {
    f4 x2 = x * x;
    f4 inner = x * (x2 * 0.044715f + 1.0f);
    f4 t = inner * -1.5957691216057308f;          // -2y
    f4 e;
    e.x = __expf(t.x); e.y = __expf(t.y);
    e.z = __expf(t.z); e.w = __expf(t.w);
    f4 den = e + 1.0f;
    f4 r;
    r.x = __builtin_amdgcn_rcpf(den.x); r.y = __builtin_amdgcn_rcpf(den.y);
    r.z = __builtin_amdgcn_rcpf(den.z); r.w = __builtin_amdgcn_rcpf(den.w);
    return x * r;                                  // x * sigmoid(2y)
}

__device__ __forceinline__ float wave_reduce_add(float v) {
#pragma unroll
    for (int m = 32; m >= 1; m >>= 1) v += __shfl_xor(v, m, 64);
    return v;
}

#if HAVE_DPP
template <int CTRL>
__device__ __forceinline__ float dpp_add(float v) {
    int t = __builtin_amdgcn_update_dpp(0, __builtin_bit_cast(int, v),
                                        CTRL, 0xf, 0xf, true);
    return v + __builtin_bit_cast(float, t);
}
// Wave-64 sum entirely on the VALU pipe (no DS ops). Valid in LANE 63 ONLY.
__device__ __forceinline__ float wave_sum_dpp_lane63(float v) {
    v = dpp_add<0x111>(v);   // row_shr:1
    v = dpp_add<0x112>(v);   // row_shr:2
    v = dpp_add<0x114>(v);   // row_shr:4
    v = dpp_add<0x118>(v);   // row_shr:8  -> lane 15 of each row16 = row sum
    v = dpp_add<0x142>(v);   // row_bcast:15 -> lane63 = row3+row2
    v = dpp_add<0x143>(v);   // row_bcast:31 -> lane63 += (row0+row1)
    return v;
}
#endif

// Prologue: pb = bf16(protos) (32 KB, cache-resident for the main kernel);
// inv_pn[k] = 1/max(||bf16(proto_k)||, eps)  (norm of the ROUNDED values).
__global__ void proto_prep_kernel(const float* __restrict__ protos,
                                  unsigned short* __restrict__ pb,
                                  float* __restrict__ inv_pn) {
    const int k = blockIdx.x;
    const int tid = threadIdx.x;
    const float* p = protos + k * DDIM;
    float ss = 0.0f;
#pragma unroll
    for (int i = 0; i < 2; ++i) {
        int idx = tid + i * 256;                       // f4 index within row
        f4 a = reinterpret_cast<const f4*>(p)[idx];
        ushort4 u;
        u.x = f32_to_bf16_rne(a.x); u.y = f32_to_bf16_rne(a.y);
        u.z = f32_to_bf16_rne(a.z); u.w = f32_to_bf16_rne(a.w);
        float q;
        q = __uint_as_float((unsigned)u.x << 16); ss += q * q;
        q = __uint_as_float((unsigned)u.y << 16); ss += q * q;
        q = __uint_as_float((unsigned)u.z << 16); ss += q * q;
        q = __uint_as_float((unsigned)u.w << 16); ss += q * q;
        *reinterpret_cast<ushort4*>(&pb[(size_t)k * DDIM + idx * 4]) = u;
    }
    ss = wave_reduce_add(ss);
    __shared__ float red[4];
    const int wave = tid >> 6, lane = tid & 63;
    if (lane == 0) red[wave] = ss;
    __syncthreads();
    if (tid == 0)
        inv_pn[k] = 1.0f / fmaxf(sqrtf(red[0] + red[1] + red[2] + red[3]), 1e-12f);
}

// R14: one block per ADJACENT row pair (16 KB contiguous), no persistent
// loop. 8192 independent blocks, 4x oversubscribed per CU -> hardware
// backfill gives phase-diverse residents that cover each other's load
// latency and serial gate windows (R10/R12/R13 lockstep-loop plateau at
// 52 us). One barrier per block lifetime.
__global__ __launch_bounds__(BLOCK)
void fused_pair_kernel(const float* __restrict__ x,
                       const unsigned short* __restrict__ pb,
                       const float* __restrict__ lt,
                       const float* __restrict__ lg,
                       const float* __restrict__ lb,
                       const float* __restrict__ inv_pn,
                       float* __restrict__ out, int nrows) {
    alignas(16) __shared__ float red[18][4];   // [value][wave]

    const int tid = threadIdx.x;
    const int lane = tid & 63;
    const int wave = tid >> 6;

    const int r0 = 2 * blockIdx.x;
    const int r1 = r0 + 1;
    if (r0 >= nrows) return;
    const bool has1 = r1 < nrows;
    const int r1c = has1 ? r1 : r0;

    // issue all 4 row loads immediately (two independent row chains)
    const f4* x0 = reinterpret_cast<const f4*>(x + (size_t)r0 * DDIM);
    const f4* x1 = reinterpret_cast<const f4*>(x + (size_t)r1c * DDIM);
    f4 a0 = x0[tid];
    f4 b0 = x0[tid + 256];
    f4 a1 = x1[tid];
    f4 b1 = x1[tid + 256];

    const float tau = __expf(lt[0]);
    const float gamma = __expf(lg[0]);
    const float alpha = 1.0f / (1.0f + __expf(-lb[0]));
    const float inv_tau = 1.0f / tau;
    const float logK_div_tau = logf(8.0f) * inv_tau;

    float ipn[KP];
#pragma unroll
    for (int k = 0; k < KP; ++k) ipn[k] = inv_pn[k];

    const uint2* pb2 = reinterpret_cast<const uint2*>(pb);  // 4 bf16 per uint2

    f4 g0a = gelu_f4(a0);
    f4 g0b = gelu_f4(b0);
    f4 g1a = gelu_f4(a1);
    f4 g1b = gelu_f4(b1);

    float vals[18];
    {
        f4 s0 = g0a * g0a + g0b * g0b;    // pk_fma-able
        f4 s1 = g1a * g1a + g1b * g1b;
        vals[8] = (s0.x + s0.y) + (s0.z + s0.w);
        vals[17] = (s1.x + s1.y) + (s1.z + s1.w);
    }

#if HAVE_DOT2
    bf2 p0a, p0b, p0c, p0d, p1a, p1b, p1c, p1d;
    p0a.x = (__bf16)g0a.x; p0a.y = (__bf16)g0a.y;
    p0b.x = (__bf16)g0a.z; p0b.y = (__bf16)g0a.w;
    p0c.x = (__bf16)g0b.x; p0c.y = (__bf16)g0b.y;
    p0d.x = (__bf16)g0b.z; p0d.y = (__bf16)g0b.w;
    p1a.x = (__bf16)g1a.x; p1a.y = (__bf16)g1a.y;
    p1b.x = (__bf16)g1a.z; p1b.y = (__bf16)g1a.w;
    p1c.x = (__bf16)g1b.x; p1c.y = (__bf16)g1b.y;
    p1d.x = (__bf16)g1b.z; p1d.y = (__bf16)g1b.w;
#pragma unroll
    for (int k = 0; k < KP; ++k) {
        uint2 q0 = pb2[k * 512 + tid];
        uint2 q1 = pb2[k * 512 + 256 + tid];
        float t0, t1;
        t0 = __builtin_amdgcn_fdot2_f32_bf16(p0a, __builtin_bit_cast(bf2, q0.x), 0.0f, false);
        t1 = __builtin_amdgcn_fdot2_f32_bf16(p1a, __builtin_bit_cast(bf2, q0.x), 0.0f, false);
        t0 = __builtin_amdgcn_fdot2_f32_bf16(p0b, __builtin_bit_cast(bf2, q0.y), t0, false);
        t1 = __builtin_amdgcn_fdot2_f32_bf16(p1b, __builtin_bit_cast(bf2, q0.y), t1, false);
        t0 = __builtin_amdgcn_fdot2_f32_bf16(p0c, __builtin_bit_cast(bf2, q1.x), t0, false);
        t1 = __builtin_amdgcn_fdot2_f32_bf16(p1c, __builtin_bit_cast(bf2, q1.x), t1, false);
        t0 = __builtin_amdgcn_fdot2_f32_bf16(p0d, __builtin_bit_cast(bf2, q1.y), t0, false);
        t1 = __builtin_amdgcn_fdot2_f32_bf16(p1d, __builtin_bit_cast(bf2, q1.y), t1, false);
        vals[k] = t0;
        vals[9 + k] = t1;
    }
#else
#pragma unroll
    for (int k = 0; k < KP; ++k) {
        uint2 q0 = pb2[k * 512 + tid];
        uint2 q1 = pb2[k * 512 + 256 + tid];
        float c0 = __uint_as_float(q0.x << 16);
        float c1 = __uint_as_float(q0.x & 0xFFFF0000u);
        float c2 = __uint_as_float(q0.y << 16);
        float c3 = __uint_as_float(q0.y & 0xFFFF0000u);
        float c4 = __uint_as_float(q1.x << 16);
        float c5 = __uint_as_float(q1.x & 0xFFFF0000u);
        float c6 = __uint_as_float(q1.y << 16);
        float c7 = __uint_as_float(q1.y & 0xFFFF0000u);
        float t0, t1;
        t0 = fmaf(c0, g0a.x, c1 * g0a.y);
        t1 = fmaf(c0, g1a.x, c1 * g1a.y);
        t0 = fmaf(c2, g0a.z, t0); t0 = fmaf(c3, g0a.w, t0);
        t1 = fmaf(c2, g1a.z, t1); t1 = fmaf(c3, g1a.w, t1);
        t0 = fmaf(c4, g0b.x, t0); t0 = fmaf(c5, g0b.y, t0);
        t1 = fmaf(c4, g1b.x, t1); t1 = fmaf(c5, g1b.y, t1);
        t0 = fmaf(c6, g0b.z, t0); t0 = fmaf(c7, g0b.w, t0);
        t1 = fmaf(c6, g1b.z, t1); t1 = fmaf(c7, g1b.w, t1);
        vals[k] = t0;
        vals[9 + k] = t1;
    }
#endif

#if HAVE_DPP
#pragma unroll
    for (int v = 0; v < 18; ++v) vals[v] = wave_sum_dpp_lane63(vals[v]);
    if (lane == 63) {
#pragma unroll
        for (int v = 0; v < 18; ++v) red[v][wave] = vals[v];
    }
#else
#pragma unroll
    for (int v = 0; v < 18; ++v) vals[v] = wave_reduce_add(vals[v]);
    if (lane == 0) {
#pragma unroll
        for (int v = 0; v < 18; ++v) red[v][wave] = vals[v];
    }
#endif
    __syncthreads();   // the ONLY barrier in the block's lifetime

    float s[18];
#pragma unroll
    for (int v = 0; v < 18; ++v) {
        f4 r = *reinterpret_cast<const f4*>(red[v]);  // broadcast b128
        s[v] = (r.x + r.y) + (r.z + r.w);
    }

    // gates, redundantly in every thread; no max-subtract (|z| <= tau)
    float gate0, gate1;
    {
        const float cn = __builtin_amdgcn_rcpf(fmaxf(sqrtf(s[8]), 1e-12f)) * tau;
        float e = 0.0f;
#pragma unroll
        for (int k = 0; k < KP; ++k)
            e += __expf(s[k] * ipn[k] * cn);
        float sms = __logf(e) * inv_tau - logK_div_tau;
        gate0 = 1.0f - alpha + alpha * __expf(-gamma * sms);
    }
    {
        const float cn = __builtin_amdgcn_rcpf(fmaxf(sqrtf(s[17]), 1e-12f)) * tau;
        float e = 0.0f;
#pragma unroll
        for (int k = 0; k < KP; ++k)
            e += __expf(s[9 + k] * ipn[k] * cn);
        float sms = __logf(e) * inv_tau - logK_div_tau;
        gate1 = 1.0f - alpha + alpha * __expf(-gamma * sms);
    }

    f4* o0 = reinterpret_cast<f4*>(out + (size_t)r0 * DDIM);
    f4 w0 = g0a * gate0;     // v_pk_mul_f32
    f4 w1 = g0b * gate0;
    __builtin_nontemporal_store(w0, &o0[tid]);
    __builtin_nontemporal_store(w1, &o0[tid + 256]);
    if (has1) {
        f4* o1 = reinterpret_cast<f4*>(out + (size_t)r1 * DDIM);
        f4 w2 = g1a * gate1;
        f4 w3 = g1b * gate1;
        __builtin_nontemporal_store(w2, &o1[tid]);
        __builtin_nontemporal_store(w3, &o1[tid + 256]);
    }
}

extern "C" void kernel_launch(void* const* d_in, const int* in_sizes, int n_in,
                              void* d_out, int out_size, void* d_ws, size_t ws_size,
                              hipStream_t stream) {
    const float* x = (const float*)d_in[0];
    const float* protos = (const float*)d_in[1];
    const float* lt = (const float*)d_in[2];
    const float* lg = (const float*)d_in[3];
    const float* lb = (const float*)d_in[4];
    float* out = (float*)d_out;

    float* inv_pn = (float*)d_ws;                                // 8 floats
    unsigned short* pb = (unsigned short*)((char*)d_ws + 256);   // 32 KB bf16 protos

    const int nrows = in_sizes[0] / DDIM;

    proto_prep_kernel<<<KP, 256, 0, stream>>>(protos, pb, inv_pn);

    // one block per adjacent row pair; HW backfill provides latency hiding
    const int blocks = (nrows + 1) / 2;
    fused_pair_kernel<<<blocks, BLOCK, 0, stream>>>(x, pb, lt, lg, lb, inv_pn,
                                                    out, nrows);
}